// Round 11
// baseline (47.419 us; speedup 1.0000x reference)
//
#include <hip/hip_runtime.h>

typedef float f2 __attribute__((ext_vector_type(2)));

// VOP3P packed f32 — inline asm because clang scalarizes generic vector IR.
static __device__ __forceinline__ f2 pk_add(f2 a, f2 b) {
    f2 d; asm("v_pk_add_f32 %0, %1, %2" : "=v"(d) : "v"(a), "v"(b)); return d;
}
static __device__ __forceinline__ f2 pk_mul(f2 a, f2 b) {
    f2 d; asm("v_pk_mul_f32 %0, %1, %2" : "=v"(d) : "v"(a), "v"(b)); return d;
}
static __device__ __forceinline__ f2 pk_fma(f2 a, f2 b, f2 c) {
    f2 d; asm("v_pk_fma_f32 %0, %1, %2, %3" : "=v"(d) : "v"(a), "v"(b), "v"(c)); return d;
}

#define H 128
#define W 128
#define HO 126
#define WO 126
#define NPIX (HO * WO)   // 15876

// One 2-row x 4-px quad: rows 2p..2p+3, cols 4xq..4xq+5 (base points there).
// Row-pairs P[i][c] = {r[i][c], r[i+1][c]} pack both output rows into VOP3P.
static __device__ __forceinline__ float grp8(const float* __restrict__ base, bool full) {
    float r[4][6];
#pragma unroll
    for (int i = 0; i < 4; ++i) {
        const float4 a = *(const float4*)(base + i * W);
        const float2 b = *(const float2*)(base + i * W + 4);
        r[i][0] = a.x; r[i][1] = a.y; r[i][2] = a.z; r[i][3] = a.w;
        r[i][4] = b.x; r[i][5] = b.y;
    }

    f2 P[3][6];
#pragma unroll
    for (int i = 0; i < 3; ++i)
#pragma unroll
        for (int c = 0; c < 6; ++c)
            P[i][c] = (f2){r[i][c], r[i + 1][c]};

    f2 cs[6], cq[6];
    float cm0[6], cm1[6];
#pragma unroll
    for (int c = 0; c < 6; ++c) {
        cs[c] = pk_add(pk_add(P[0][c], P[1][c]), P[2][c]);
        cq[c] = pk_fma(P[2][c], P[2][c], pk_fma(P[1][c], P[1][c], pk_mul(P[0][c], P[0][c])));
        cm0[c] = fmaxf(r[0][c], fmaxf(r[1][c], r[2][c]));   // -> v_max3
        cm1[c] = fmaxf(r[1][c], fmaxf(r[2][c], r[3][c]));
    }

    const f2 M1 = {-1.f, -1.f};
    const f2 C9 = {9.f, 9.f};

    float b01 = 0.f, b23 = 0.f;
#pragma unroll
    for (int k = 0; k < 4; ++k) {
        const f2 sum = pk_add(pk_add(cs[k], cs[k + 1]), cs[k + 2]);
        const f2 ssq = pk_add(pk_add(cq[k], cq[k + 1]), cq[k + 2]);
        const float wm0 = fmaxf(cm0[k], fmaxf(cm0[k + 1], cm0[k + 2]));
        const float wm1 = fmaxf(cm1[k], fmaxf(cm1[k + 1], cm1[k + 2]));

        const f2 nctr = pk_mul(P[1][k + 1], M1);
        const f2 d00 = pk_add(P[0][k],     nctr);
        const f2 d01 = pk_add(P[0][k + 1], nctr);
        const f2 d02 = pk_add(P[0][k + 2], nctr);
        const f2 d10 = pk_add(P[1][k],     nctr);
        const f2 d12 = pk_add(P[1][k + 2], nctr);
        const f2 d20 = pk_add(P[2][k],     nctr);
        const f2 d21 = pk_add(P[2][k + 1], nctr);
        const f2 d22 = pk_add(P[2][k + 2], nctr);

        // fabs folds into VOP3 add input modifiers (free)
        const float sad0 = ((fabsf(d00.x) + fabsf(d01.x)) + (fabsf(d02.x) + fabsf(d10.x)))
                         + ((fabsf(d12.x) + fabsf(d20.x)) + (fabsf(d21.x) + fabsf(d22.x)));
        const float sad1 = ((fabsf(d00.y) + fabsf(d01.y)) + (fabsf(d02.y) + fabsf(d10.y)))
                         + ((fabsf(d12.y) + fabsf(d20.y)) + (fabsf(d21.y) + fabsf(d22.y)));
        const float thr0 = sad0 * (1.f / 9.f);
        const float thr1 = sad1 * (1.f / 9.f);

        int c0 = (sad0 <= 0.f) ? 1 : 0;   // center tap: 0 >= thr
        c0 += d00.x >= thr0; c0 += d01.x >= thr0; c0 += d02.x >= thr0; c0 += d10.x >= thr0;
        c0 += d12.x >= thr0; c0 += d20.x >= thr0; c0 += d21.x >= thr0; c0 += d22.x >= thr0;
        int c1 = (sad1 <= 0.f) ? 1 : 0;
        c1 += d00.y >= thr1; c1 += d01.y >= thr1; c1 += d02.y >= thr1; c1 += d10.y >= thr1;
        c1 += d12.y >= thr1; c1 += d20.y >= thr1; c1 += d21.y >= thr1; c1 += d22.y >= thr1;

        const f2 var81 = pk_fma(sum, pk_mul(sum, M1), pk_mul(ssq, C9));  // 81*var
        const float sd0 = __builtin_amdgcn_sqrtf(fmaxf(var81.x, 0.f));   // 9*std
        const float sd1 = __builtin_amdgcn_sqrtf(fmaxf(var81.y, 0.f));
        const float nf0 = fmaf(sum.x, -1.f / 2295.f, (float)c0 * (1.f / 255.f));
        const float nf1 = fmaf(sum.y, -1.f / 2295.f, (float)c1 * (1.f / 255.f));
        const float bn0 = fmaf(nf0, fmaf(sd0, 1.f / 9.f, -wm0), wm0);
        const float bn1 = fmaf(nf1, fmaf(sd1, 1.f / 9.f, -wm1), wm1);

        if (k < 2) b01 += bn0 + bn1;
        else       b23 += bn0 + bn1;
    }
    return full ? (b01 + b23) : b01;   // xq==31: px 2,3 out of range
}

// One block = one plane (single dispatch, no atomics). 512 threads:
// xq = t&31 (4-px strip), p0 = t>>5; y-pairs p0+16i, i=0..3 (i=3 iff p0<15)
// cover all 63 pairs exactly once. One base reg; ds_reads use imm offsets.
__global__ __launch_bounds__(512, 4) void bp_kernel(const float* __restrict__ x,
                                                    float* __restrict__ out) {
    __shared__ float tile[H * W + 8];   // +8: xq==31 float2 tail lands in pad
    __shared__ float wred[8];

    const int t     = threadIdx.x;
    const int plane = blockIdx.x;

    // ---- stage full 64 KiB plane (8 coalesced float4 per thread) ----
    const float4* s4 = (const float4*)(x + (size_t)plane * (H * W));
    float4* t4 = (float4*)tile;
#pragma unroll
    for (int i = 0; i < 8; ++i)
        t4[t + 512 * i] = s4[t + 512 * i];
    if (t < 8) tile[H * W + t] = 0.f;
    __syncthreads();

    const int xq = t & 31;
    const int p0 = t >> 5;
    const bool full = (xq != 31);
    const float* base = tile + p0 * 256 + xq * 4;   // row 2*p0, col 4*xq

    float acc = grp8(base, full) + grp8(base + 4096, full) + grp8(base + 8192, full);
    if (p0 < 15)                                     // pair p0+48 <= 62
        acc += grp8(base + 12288, full);

    // ---- reduction: 8 waves ----
#pragma unroll
    for (int off = 32; off > 0; off >>= 1)
        acc += __shfl_down(acc, off, 64);
    if ((t & 63) == 0) wred[t >> 6] = acc;
    __syncthreads();
    if (t < 64) {
        float v = (t < 8) ? wred[t] : 0.f;
        v += __shfl_down(v, 4, 64);
        v += __shfl_down(v, 2, 64);
        v += __shfl_down(v, 1, 64);
        if (t == 0) out[plane] = v * (1.f / NPIX);
    }
}

extern "C" void kernel_launch(void* const* d_in, const int* in_sizes, int n_in,
                              void* d_out, int out_size, void* d_ws, size_t ws_size,
                              hipStream_t stream) {
    const float* x = (const float*)d_in[0];
    float* out = (float*)d_out;
    bp_kernel<<<dim3(16 * 64), dim3(512), 0, stream>>>(x, out);
}

// Round 12
// 43.587 us; speedup vs baseline: 1.0879x; 1.0879x over previous
//
#include <hip/hip_runtime.h>

#define H     128
#define W     128
#define HO    126
#define WO    126
#define NPIX  (HO * WO)      // 15876
#define LW    168            // LDS row stride (floats); 128*168*4 = 86 KB > 80 KB
                             // -> only 1 block/CU fits -> compiler has no reason
                             // to squeeze VGPR below the 4-waves/SIMD cap (128)

// 8-px group: rows y..y+2, cols x0..x0+9 (float base given). Returns sum of
// valid bn (px 0..5 always valid; px 6,7 iff full).
static __device__ __forceinline__ float grp8(const float* __restrict__ base, bool full) {
    float r[3][10];
#pragma unroll
    for (int i = 0; i < 3; ++i) {
        const float* p = base + i * LW;
        const float4 a = *(const float4*)p;
        const float4 b = *(const float4*)(p + 4);
        const float2 e = *(const float2*)(p + 8);
        r[i][0] = a.x; r[i][1] = a.y; r[i][2] = a.z; r[i][3] = a.w;
        r[i][4] = b.x; r[i][5] = b.y; r[i][6] = b.z; r[i][7] = b.w;
        r[i][8] = e.x; r[i][9] = e.y;
    }

    float cs[10], cq[10], cm[10];
#pragma unroll
    for (int c = 0; c < 10; ++c) {
        cs[c] = r[0][c] + r[1][c] + r[2][c];
        cq[c] = fmaf(r[0][c], r[0][c], fmaf(r[1][c], r[1][c], r[2][c] * r[2][c]));
        cm[c] = fmaxf(r[0][c], fmaxf(r[1][c], r[2][c]));   // -> v_max3
    }

    float s05 = 0.f, s67 = 0.f;
#pragma unroll
    for (int k = 0; k < 8; ++k) {
        const float ctr  = r[1][k + 1];
        const float sum  = cs[k] + cs[k + 1] + cs[k + 2];
        const float ss   = cq[k] + cq[k + 1] + cq[k + 2];
        const float wmax = fmaxf(cm[k], fmaxf(cm[k + 1], cm[k + 2]));

        float d[8];
        d[0] = r[0][k]     - ctr;  d[1] = r[0][k + 1] - ctr;
        d[2] = r[0][k + 2] - ctr;  d[3] = r[1][k]     - ctr;
        d[4] = r[1][k + 2] - ctr;  d[5] = r[2][k]     - ctr;
        d[6] = r[2][k + 1] - ctr;  d[7] = r[2][k + 2] - ctr;

        const float sad = ((fabsf(d[0]) + fabsf(d[1])) + (fabsf(d[2]) + fabsf(d[3])))
                        + ((fabsf(d[4]) + fabsf(d[5])) + (fabsf(d[6]) + fabsf(d[7])));
        const float thr = sad * (1.f / 9.f);

        int b0 = (sad <= 0.f) ? 1 : 0;   // center tap: 0 >= thr
        b0 += d[0] >= thr;
        b0 += d[1] >= thr;
        b0 += d[2] >= thr;
        b0 += d[3] >= thr;
        int b1 = d[4] >= thr;
        b1 += d[5] >= thr;
        b1 += d[6] >= thr;
        b1 += d[7] >= thr;
        const float bv = (float)(b0 + b1);

        const float var9 = fmaf(sum, -sum, 9.f * ss);                // 81*var
        const float sd9  = __builtin_amdgcn_sqrtf(fmaxf(var9, 0.f)); // 9*std
        const float nf   = fmaf(sum, -1.f / 2295.f, bv * (1.f / 255.f));
        const float bn   = fmaf(nf, fmaf(sd9, 1.f / 9.f, -wmax), wmax);

        if (k < 6) s05 += bn;
        else       s67 += bn;
    }
    return s05 + (full ? s67 : 0.f);   // NaN from garbage cols discarded by select
}

// One block = one plane, single dispatch. Thread t: xq = t&15 (8-px strip),
// y = t>>4; pass 0 covers rows 0..63, pass 1 rows 64..125 (t<992).
__global__ __launch_bounds__(1024, 1) void bp_kernel(const float* __restrict__ x,
                                                     float* __restrict__ out) {
    __shared__ float tile[H * LW];   // 86 KB: row stride 168
    __shared__ float wred[16];

    const int t     = threadIdx.x;
    const int plane = blockIdx.x;

    // ---- stage plane: 4 coalesced float4 per thread, rows restrided to LW ----
    const float4* s4 = (const float4*)(x + (size_t)plane * (H * W));
    float4* t4 = (float4*)tile;
#pragma unroll
    for (int kk = 0; kk < 4; ++kk) {
        const int i = t + 1024 * kk;
        const int y = i >> 5, j = i & 31;
        t4[y * (LW / 4) + j] = s4[i];
    }
    // zero the two garbage columns the xq==15 window touches (cols 128,129)
    if (t < H) {
        tile[t * LW + 128] = 0.f;
        tile[t * LW + 129] = 0.f;
    }
    __syncthreads();

    const int xq  = t & 15;
    const int y0  = t >> 4;            // rows 0..63
    const bool full = (xq != 15);      // WO=126=15*8+6: strip 15 keeps px 0..5
    const float* base = tile + y0 * LW + xq * 8;

    float acc = grp8(base, full);
    if (t < 992)                        // y1 = y0+64 <= 125
        acc += grp8(base + 64 * LW, full);

    // ---- reduction: 16 waves ----
#pragma unroll
    for (int off = 32; off > 0; off >>= 1)
        acc += __shfl_down(acc, off, 64);
    if ((t & 63) == 0) wred[t >> 6] = acc;
    __syncthreads();
    if (t < 64) {
        float v = (t < 16) ? wred[t] : 0.f;
        v += __shfl_down(v, 8, 64);
        v += __shfl_down(v, 4, 64);
        v += __shfl_down(v, 2, 64);
        v += __shfl_down(v, 1, 64);
        if (t == 0) out[plane] = v * (1.f / NPIX);
    }
}

extern "C" void kernel_launch(void* const* d_in, const int* in_sizes, int n_in,
                              void* d_out, int out_size, void* d_ws, size_t ws_size,
                              hipStream_t stream) {
    const float* x = (const float*)d_in[0];
    float* out = (float*)d_out;
    bp_kernel<<<dim3(16 * 64), dim3(1024), 0, stream>>>(x, out);
}

// Round 13
// 36.496 us; speedup vs baseline: 1.2993x; 1.1943x over previous
//
#include <hip/hip_runtime.h>

#define H     128
#define W     128
#define HO    126
#define WO    126
#define NPIX  (HO * WO)      // 15876
#define LW    128            // LDS row stride
#define BROWS 18             // staged rows per chunk buffer
#define BSZ   (BROWS * LW + 8)

// 8-px group: rows y..y+2, cols x0..x0+9. px 0..5 always valid; 6,7 iff full.
static __device__ __forceinline__ float grp8(const float* __restrict__ base, bool full) {
    float r[3][10];
#pragma unroll
    for (int i = 0; i < 3; ++i) {
        const float* p = base + i * LW;
        const float4 a = *(const float4*)p;
        const float4 b = *(const float4*)(p + 4);
        const float2 e = *(const float2*)(p + 8);
        r[i][0] = a.x; r[i][1] = a.y; r[i][2] = a.z; r[i][3] = a.w;
        r[i][4] = b.x; r[i][5] = b.y; r[i][6] = b.z; r[i][7] = b.w;
        r[i][8] = e.x; r[i][9] = e.y;
    }

    float cs[10], cq[10], cm[10];
#pragma unroll
    for (int c = 0; c < 10; ++c) {
        cs[c] = r[0][c] + r[1][c] + r[2][c];
        cq[c] = fmaf(r[0][c], r[0][c], fmaf(r[1][c], r[1][c], r[2][c] * r[2][c]));
        cm[c] = fmaxf(r[0][c], fmaxf(r[1][c], r[2][c]));   // -> v_max3
    }

    float s05 = 0.f, s67 = 0.f;
#pragma unroll
    for (int k = 0; k < 8; ++k) {
        const float ctr  = r[1][k + 1];
        const float sum  = cs[k] + cs[k + 1] + cs[k + 2];
        const float ss   = cq[k] + cq[k + 1] + cq[k + 2];
        const float wmax = fmaxf(cm[k], fmaxf(cm[k + 1], cm[k + 2]));

        float d[8];
        d[0] = r[0][k]     - ctr;  d[1] = r[0][k + 1] - ctr;
        d[2] = r[0][k + 2] - ctr;  d[3] = r[1][k]     - ctr;
        d[4] = r[1][k + 2] - ctr;  d[5] = r[2][k]     - ctr;
        d[6] = r[2][k + 1] - ctr;  d[7] = r[2][k + 2] - ctr;

        const float sad = ((fabsf(d[0]) + fabsf(d[1])) + (fabsf(d[2]) + fabsf(d[3])))
                        + ((fabsf(d[4]) + fabsf(d[5])) + (fabsf(d[6]) + fabsf(d[7])));
        const float thr = sad * (1.f / 9.f);

        int b0 = (sad <= 0.f) ? 1 : 0;   // center tap: 0 >= thr
        b0 += d[0] >= thr;
        b0 += d[1] >= thr;
        b0 += d[2] >= thr;
        b0 += d[3] >= thr;
        int b1 = d[4] >= thr;
        b1 += d[5] >= thr;
        b1 += d[6] >= thr;
        b1 += d[7] >= thr;
        const float bv = (float)(b0 + b1);

        const float var9 = fmaf(sum, -sum, 9.f * ss);                // 81*var
        const float sd9  = __builtin_amdgcn_sqrtf(fmaxf(var9, 0.f)); // 9*std
        const float nf   = fmaf(sum, -1.f / 2295.f, bv * (1.f / 255.f));
        const float bn   = fmaf(nf, fmaf(sd9, 1.f / 9.f, -wmax), wmax);

        if (k < 6) s05 += bn;
        else       s67 += bn;
    }
    return s05 + (full ? s67 : 0.f);
}

// One block = one plane, 256 threads, single dispatch (grid 1024 = exactly
// 4 blocks/CU, one round). 8 chunks of 16 output rows; double-buffered LDS
// with reg-staged pipeline: issue chunk c+1 loads -> compute chunk c (hides
// HBM/L3 latency) -> ds_write chunk c+1 -> one barrier.
__global__ __launch_bounds__(256, 4) void bp_kernel(const float* __restrict__ x,
                                                    float* __restrict__ out) {
    __shared__ float buf[2][BSZ];
    __shared__ float wred[4];

    const int t     = threadIdx.x;
    const int plane = blockIdx.x;
    const float4* s4 = (const float4*)(x + (size_t)plane * (H * W));

    // ---- prologue: stage chunk 0 (18 rows = 576 float4) into buf0 ----
    {
        float4 g0 = s4[t], g1 = s4[t + 256], g2;
        if (t < 64) g2 = s4[t + 512];
        float4* b4 = (float4*)buf[0];
        b4[t] = g0; b4[t + 256] = g1;
        if (t < 64) b4[t + 512] = g2;
    }
    __syncthreads();

    const int y  = t >> 4;        // group row within chunk (0..15)
    const int xq = t & 15;        // 8-px strip (0..15)
    const bool full = (xq != 15); // WO = 126 = 15*8 + 6
    const int goff = y * LW + xq * 8;

    float acc = 0.f;

#pragma unroll 2
    for (int c = 0; c < 8; ++c) {
        float4 g0, g1, g2;
        const bool pre   = (c < 7);
        const bool third = (c < 6);          // chunk 7 stages only 16 rows (512 f4)
        if (pre) {
            const int base = (c + 1) * 512;  // chunk starts at row 16(c+1)
            g0 = s4[base + t];
            g1 = s4[base + t + 256];
            if (third && t < 64) g2 = s4[base + t + 512];
        }

        // compute chunk c from buf[c&1] (chunk 7: only 14 output rows)
        if (c < 7 || y < 14)
            acc += grp8(&buf[c & 1][goff], full);

        if (pre) {
            float4* d4 = (float4*)buf[(c + 1) & 1];
            d4[t] = g0; d4[t + 256] = g1;        // vmcnt wait lands here
            if (third && t < 64) d4[t + 512] = g2;
        }
        __syncthreads();
    }

    // ---- reduction: 4 waves ----
#pragma unroll
    for (int off = 32; off > 0; off >>= 1)
        acc += __shfl_down(acc, off, 64);
    if ((t & 63) == 0) wred[t >> 6] = acc;
    __syncthreads();
    if (t < 64) {
        float v = (t < 4) ? wred[t] : 0.f;
        v += __shfl_down(v, 2, 64);
        v += __shfl_down(v, 1, 64);
        if (t == 0) out[plane] = v * (1.f / NPIX);
    }
}

extern "C" void kernel_launch(void* const* d_in, const int* in_sizes, int n_in,
                              void* d_out, int out_size, void* d_ws, size_t ws_size,
                              hipStream_t stream) {
    const float* x = (const float*)d_in[0];
    float* out = (float*)d_out;
    bp_kernel<<<dim3(16 * 64), dim3(256), 0, stream>>>(x, out);
}

// Round 14
// 36.476 us; speedup vs baseline: 1.3000x; 1.0005x over previous
//
#include <hip/hip_runtime.h>

#define H     128
#define W     128
#define HO    126
#define WO    126
#define NPIX  (HO * WO)      // 15876
#define LW    128            // LDS row stride
#define BROWS 18             // staged rows per chunk buffer
#define BSZ   (BROWS * LW + 8)

// 8-px group: rows y..y+2, cols x0..x0+9. px 0..5 always valid; 6,7 iff full.
static __device__ __forceinline__ float grp8(const float* __restrict__ base, bool full) {
    float r[3][10];
#pragma unroll
    for (int i = 0; i < 3; ++i) {
        const float* p = base + i * LW;
        const float4 a = *(const float4*)p;
        const float4 b = *(const float4*)(p + 4);
        const float2 e = *(const float2*)(p + 8);
        r[i][0] = a.x; r[i][1] = a.y; r[i][2] = a.z; r[i][3] = a.w;
        r[i][4] = b.x; r[i][5] = b.y; r[i][6] = b.z; r[i][7] = b.w;
        r[i][8] = e.x; r[i][9] = e.y;
    }

    float cs[10], cq[10], cm[10];
#pragma unroll
    for (int c = 0; c < 10; ++c) {
        cs[c] = r[0][c] + r[1][c] + r[2][c];
        cq[c] = fmaf(r[0][c], r[0][c], fmaf(r[1][c], r[1][c], r[2][c] * r[2][c]));
        cm[c] = fmaxf(r[0][c], fmaxf(r[1][c], r[2][c]));   // -> v_max3
    }

    float s05 = 0.f, s67 = 0.f;
#pragma unroll
    for (int k = 0; k < 8; ++k) {
        const float ctr  = r[1][k + 1];
        const float sum  = cs[k] + cs[k + 1] + cs[k + 2];
        const float ss   = cq[k] + cq[k + 1] + cq[k + 2];
        const float wmax = fmaxf(cm[k], fmaxf(cm[k + 1], cm[k + 2]));

        float d[8];
        d[0] = r[0][k]     - ctr;  d[1] = r[0][k + 1] - ctr;
        d[2] = r[0][k + 2] - ctr;  d[3] = r[1][k]     - ctr;
        d[4] = r[1][k + 2] - ctr;  d[5] = r[2][k]     - ctr;
        d[6] = r[2][k + 1] - ctr;  d[7] = r[2][k + 2] - ctr;

        const float sad = ((fabsf(d[0]) + fabsf(d[1])) + (fabsf(d[2]) + fabsf(d[3])))
                        + ((fabsf(d[4]) + fabsf(d[5])) + (fabsf(d[6]) + fabsf(d[7])));
        const float thr = sad * (1.f / 9.f);

        int b0 = (sad <= 0.f) ? 1 : 0;   // center tap: 0 >= thr
        b0 += d[0] >= thr;
        b0 += d[1] >= thr;
        b0 += d[2] >= thr;
        b0 += d[3] >= thr;
        int b1 = d[4] >= thr;
        b1 += d[5] >= thr;
        b1 += d[6] >= thr;
        b1 += d[7] >= thr;
        const float bv = (float)(b0 + b1);

        const float var9 = fmaf(sum, -sum, 9.f * ss);                // 81*var
        const float sd9  = __builtin_amdgcn_sqrtf(fmaxf(var9, 0.f)); // 9*std
        const float nf   = fmaf(sum, -1.f / 2295.f, bv * (1.f / 255.f));
        const float bn   = fmaf(nf, fmaf(sd9, 1.f / 9.f, -wmax), wmax);

        if (k < 6) s05 += bn;
        else       s67 += bn;
    }
    return s05 + (full ? s67 : 0.f);
}

// One block = one 63-row half-plane. 2048 blocks x 256 thr = 8 blocks/CU
// (LDS 18.9 KB x 8 = 151 KB) = 32 waves/CU, exactly one round.
// 4 pipelined chunks (16,16,16,15 output rows), double-buffered LDS.
__global__ __launch_bounds__(256, 4) void bp_kernel(const float* __restrict__ x,
                                                    float* __restrict__ ws) {
    __shared__ float buf[2][BSZ];
    __shared__ float wred[4];

    const int t     = threadIdx.x;
    const int bid   = blockIdx.x;
    const int plane = bid >> 1;
    const int half  = bid & 1;
    // first output row of this half = 63*half; staged f4s start at that row
    const float4* s4 = (const float4*)(x + (size_t)plane * (H * W)) + (63 * half) * 32;

    // ---- prologue: stage chunk 0 (18 rows = 576 float4) into buf0 ----
    {
        float4 g0 = s4[t], g1 = s4[t + 256], g2;
        if (t < 64) g2 = s4[t + 512];
        float4* b4 = (float4*)buf[0];
        b4[t] = g0; b4[t + 256] = g1;
        if (t < 64) b4[t + 512] = g2;
    }
    __syncthreads();

    const int y  = t >> 4;        // group row within chunk (0..15)
    const int xq = t & 15;        // 8-px strip
    const bool full = (xq != 15); // WO = 126 = 15*8 + 6
    const int goff = y * LW + xq * 8;

    float acc = 0.f;

#pragma unroll
    for (int c = 0; c < 4; ++c) {
        float4 g0, g1, g2;
        const bool pre = (c < 3);
        const int  nthird = (c == 2) ? 32 : 64;   // chunk 3 stages 17 rows (544 f4)
        if (pre) {
            const int base = (c + 1) * 512;        // chunk c+1 starts 16 rows later
            g0 = s4[base + t];
            g1 = s4[base + t + 256];
            if (t < nthird) g2 = s4[base + t + 512];
        }

        // compute chunk c from buf[c&1] (chunk 3: only 15 output rows)
        if (c < 3 || y < 15)
            acc += grp8(&buf[c & 1][goff], full);

        if (pre) {
            float4* d4 = (float4*)buf[(c + 1) & 1];
            d4[t] = g0; d4[t + 256] = g1;          // vmcnt wait lands here
            if (t < nthird) d4[t + 512] = g2;
        }
        __syncthreads();
    }

    // ---- reduction: 4 waves -> ws[bid] ----
#pragma unroll
    for (int off = 32; off > 0; off >>= 1)
        acc += __shfl_down(acc, off, 64);
    if ((t & 63) == 0) wred[t >> 6] = acc;
    __syncthreads();
    if (t == 0)
        ws[bid] = wred[0] + wred[1] + wred[2] + wred[3];
}

// fold the two half-plane partials -> mean
__global__ __launch_bounds__(1024) void combine(const float* __restrict__ ws,
                                                float* __restrict__ out) {
    const int p = threadIdx.x;
    out[p] = (ws[2 * p] + ws[2 * p + 1]) * (1.f / NPIX);
}

extern "C" void kernel_launch(void* const* d_in, const int* in_sizes, int n_in,
                              void* d_out, int out_size, void* d_ws, size_t ws_size,
                              hipStream_t stream) {
    const float* x = (const float*)d_in[0];
    float* out = (float*)d_out;
    float* ws  = (float*)d_ws;
    bp_kernel<<<dim3(2048), dim3(256), 0, stream>>>(x, ws);
    combine<<<dim3(1), dim3(1024), 0, stream>>>(ws, out);
}